// Round 2
// baseline (6401.022 us; speedup 1.0000x reference)
//
#include <hip/hip_runtime.h>
#include <hip/hip_bf16.h>
#include <hip/hip_cooperative_groups.h>
#include <cstdint>
#include <cstddef>

namespace cg = cooperative_groups;

// Problem constants (match reference)
#define Hdim 1024
#define Vdim 32000
#define LAYERS 3
#define Bdim 64
#define Tdim 32
#define BT 2048      // B*T
#define G3H 3072     // 3*H

using bf16 = __bf16;
using bf16x8 = __attribute__((ext_vector_type(8))) __bf16;  // one MFMA A/B fragment (4 VGPRs)
using bf16x4 = __attribute__((ext_vector_type(4))) __bf16;
using f32x4  = __attribute__((ext_vector_type(4))) float;

// async global->LDS, 16B per lane. LDS dest must be wave-uniform-base + lane*16.
typedef __attribute__((address_space(3))) unsigned int lds_u32;
typedef __attribute__((address_space(1))) const unsigned int glb_u32;
__device__ __forceinline__ void gll16(const void* g, void* l) {
  __builtin_amdgcn_global_load_lds((glb_u32*)g, (lds_u32*)l, 16, 0, 0);
}

// ---------------- fp32 -> bf16 conversion (weights) ----------------
__global__ __launch_bounds__(256) void cvt_f32_bf16(const float* __restrict__ src,
                                                    bf16* __restrict__ dst, int n4) {
  int i = blockIdx.x * 256 + threadIdx.x;
  if (i < n4) {
    f32x4 v = ((const f32x4*)src)[i];
    bf16x4 o;
    o[0] = (bf16)v[0]; o[1] = (bf16)v[1]; o[2] = (bf16)v[2]; o[3] = (bf16)v[3];
    ((bf16x4*)dst)[i] = o;
  }
}

// ---------------- embedding + relu -> bf16 x0 ----------------
__global__ __launch_bounds__(256) void embed_relu(const int* __restrict__ tgt,
                                                  const float* __restrict__ emb,
                                                  bf16* __restrict__ x) {
  int row = blockIdx.x;
  int b = row >> 5, t = row & 31;
  int id = (t == 0) ? 0 : tgt[b * Tdim + t - 1];
  const f32x4* src = (const f32x4*)(emb + (size_t)id * Hdim);
  bf16x4* dst = (bf16x4*)(x + (size_t)row * Hdim);
  f32x4 v = src[threadIdx.x];
  bf16x4 o;
  o[0] = (bf16)fmaxf(v[0], 0.f); o[1] = (bf16)fmaxf(v[1], 0.f);
  o[2] = (bf16)fmaxf(v[2], 0.f); o[3] = (bf16)fmaxf(v[3], 0.f);
  dst[threadIdx.x] = o;
}

// ---------------- C = A @ W^T + bias  (m97-style LDS GEMM) ----------------
// A: [M,K] bf16 row-major. W: [N,K] bf16 row-major. C: [M,N] fp32.
// 256 thr = 4 waves (2x2), block tile 128x128, wave tile 64x64 (4x4 MFMA 16x16x32),
// BK=32, single LDS buffer, 2-barrier K-loop, global_load_lds dwordx4 staging.
__global__ __launch_bounds__(256) void gemm_lds(const bf16* __restrict__ A,
                                                const bf16* __restrict__ W,
                                                const float* __restrict__ bias,
                                                float* __restrict__ C,
                                                int M, int N, int K) {
  __shared__ __align__(16) bf16 As[128 * 32];
  __shared__ __align__(16) bf16 Bs[128 * 32];
  int tid = threadIdx.x;
  int wave = tid >> 6, lane = tid & 63;
  int lane15 = lane & 15, quad = lane >> 4;
  int wr = wave >> 1, wc = wave & 1;
  int m0 = blockIdx.y * 128, n0 = blockIdx.x * 128;
  // staging: 512 16B-chunks per tile; chunk c -> row c>>2, k-part c&3.
  int c0 = tid, c1 = tid + 256;
  int r0 = c0 >> 2, p0 = c0 & 3, r1 = c1 >> 2, p1 = c1 & 3;
  const bf16* Ab = A + (size_t)m0 * K;
  const bf16* Wb = W + (size_t)n0 * K;

  f32x4 acc[4][4] = {};
  for (int k0 = 0; k0 < K; k0 += 32) {
    __syncthreads();  // previous iter's LDS readers done
    gll16(Ab + (size_t)r0 * K + k0 + p0 * 8, As + c0 * 8);
    gll16(Ab + (size_t)r1 * K + k0 + p1 * 8, As + c1 * 8);
    gll16(Wb + (size_t)r0 * K + k0 + p0 * 8, Bs + c0 * 8);
    gll16(Wb + (size_t)r1 * K + k0 + p1 * 8, Bs + c1 * 8);
    __syncthreads();  // drains vmcnt(0) then barrier
    bf16x8 a[4], b[4];
#pragma unroll
    for (int mi = 0; mi < 4; mi++)
      a[mi] = *(const bf16x8*)(As + (wr * 64 + mi * 16 + lane15) * 32 + quad * 8);
#pragma unroll
    for (int ni = 0; ni < 4; ni++)
      b[ni] = *(const bf16x8*)(Bs + (wc * 64 + ni * 16 + lane15) * 32 + quad * 8);
#pragma unroll
    for (int mi = 0; mi < 4; mi++)
#pragma unroll
      for (int ni = 0; ni < 4; ni++)
        acc[mi][ni] = __builtin_amdgcn_mfma_f32_16x16x32_bf16(a[mi], b[ni], acc[mi][ni], 0, 0, 0);
  }
#pragma unroll
  for (int mi = 0; mi < 4; mi++)
#pragma unroll
    for (int ni = 0; ni < 4; ni++) {
      int col = n0 + wc * 64 + ni * 16 + lane15;
      float bv = bias[col];
#pragma unroll
      for (int r = 0; r < 4; r++) {
        int row = m0 + wr * 64 + mi * 16 + quad * 4 + r;
        C[(size_t)row * N + col] = acc[mi][ni][r] + bv;
      }
    }
}

// ---------------- persistent per-layer GRU (cooperative) ----------------
// 256 blocks x 256 thr; block (ib=bx>>2, bb=bx&3) owns the 16(b) x 16(i) patch.
// Whh slice (3 gates x 16 rows x 1024) cached in LDS once (fp32->bf16 fused),
// padded stride 1032 (2-way banks = free). 4 waves K-split 256 each, LDS-reduce,
// wave 0 gate epilogue, h ping-pong in global, __threadfence + grid.sync per step.
#define WSTRIDE 1032
__global__ __launch_bounds__(256) void gru_layer(
    const float* __restrict__ eh,    // encoder_hidden[l] [B,H]
    const float* __restrict__ Whh,   // [3H,H] fp32
    const float* __restrict__ bhh,   // [3H]
    const float* __restrict__ xp,    // [BT,3H] fp32
    float* h32a, float* h32b, bf16* hbfa, bf16* hbfb,
    bf16* __restrict__ y,            // [BT,H] bf16 (layer output)
    float* __restrict__ finals) {    // [B,H] (d_out slice)
  __shared__ __align__(16) bf16 wlds[48 * WSTRIDE];   // 99072 B
  __shared__ f32x4 red[4][3][64];                     // 12288 B
  cg::grid_group grid = cg::this_grid();

  int tid = threadIdx.x;
  int wave = tid >> 6, lane = tid & 63;
  int lane15 = lane & 15, quad = lane >> 4;
  int ib = blockIdx.x >> 2, bb = blockIdx.x & 3;
  int i0 = ib * 16, b0 = bb * 16;

  // stage Whh slice (48 rows x 1024) fp32 -> bf16 into padded LDS
  for (int idx = tid; idx < 48 * 256; idx += 256) {
    int row = idx >> 8, c = idx & 255;            // 256 f32x4 chunks per row
    int g = row >> 4, rr = row & 15;
    f32x4 v = *(const f32x4*)(Whh + (size_t)(g * Hdim + i0 + rr) * Hdim + c * 4);
    bf16x4 o;
    o[0] = (bf16)v[0]; o[1] = (bf16)v[1]; o[2] = (bf16)v[2]; o[3] = (bf16)v[3];
    *(bf16x4*)(wlds + row * WSTRIDE + c * 4) = o;
  }
  // init h ping buffer from encoder_hidden: this block's 16x16 patch
  {
    int r = tid >> 4, c = tid & 15;
    float v = eh[(size_t)(b0 + r) * Hdim + i0 + c];
    h32a[(size_t)(b0 + r) * Hdim + i0 + c] = v;
    hbfa[(size_t)(b0 + r) * Hdim + i0 + c] = (bf16)v;
  }
  float bhr = bhh[i0 + lane15];
  float bhz = bhh[Hdim + i0 + lane15];
  float bhn = bhh[2 * Hdim + i0 + lane15];
  __threadfence();
  grid.sync();

  for (int t = 0; t < Tdim; t++) {
    const bf16* hbf_p = (t & 1) ? hbfb : hbfa;
    const float* h32_p = (t & 1) ? h32b : h32a;
    bf16* hbf_n = (t & 1) ? hbfa : hbfb;
    float* h32_n = (t & 1) ? h32a : h32b;

    f32x4 ar = {}, az = {}, an = {};
    const bf16* Ap = hbf_p + (size_t)(b0 + lane15) * Hdim + wave * 256 + quad * 8;
    const bf16* wl = wlds + lane15 * WSTRIDE + wave * 256 + quad * 8;
#pragma unroll
    for (int kk = 0; kk < 256; kk += 32) {
      bf16x8 a  = *(const bf16x8*)(Ap + kk);
      bf16x8 br = *(const bf16x8*)(wl + kk);
      bf16x8 bz = *(const bf16x8*)(wl + 16 * WSTRIDE + kk);
      bf16x8 bn = *(const bf16x8*)(wl + 32 * WSTRIDE + kk);
      ar = __builtin_amdgcn_mfma_f32_16x16x32_bf16(a, br, ar, 0, 0, 0);
      az = __builtin_amdgcn_mfma_f32_16x16x32_bf16(a, bz, az, 0, 0, 0);
      an = __builtin_amdgcn_mfma_f32_16x16x32_bf16(a, bn, an, 0, 0, 0);
    }
    red[wave][0][lane] = ar;
    red[wave][1][lane] = az;
    red[wave][2][lane] = an;
    __syncthreads();
    if (wave == 0) {
      f32x4 sr = red[0][0][lane] + red[1][0][lane] + red[2][0][lane] + red[3][0][lane];
      f32x4 sz = red[0][1][lane] + red[1][1][lane] + red[2][1][lane] + red[3][1][lane];
      f32x4 sn = red[0][2][lane] + red[1][2][lane] + red[2][2][lane] + red[3][2][lane];
      int i = i0 + lane15;
#pragma unroll
      for (int r = 0; r < 4; r++) {
        int b = b0 + quad * 4 + r;
        size_t m = (size_t)b * Tdim + t;
        float xr = xp[m * G3H + i];
        float xz = xp[m * G3H + Hdim + i];
        float xn = xp[m * G3H + 2 * Hdim + i];
        float hpr = sr[r] + bhr, hpz = sz[r] + bhz, hpn = sn[r] + bhn;
        float rg = 1.f / (1.f + __expf(-(xr + hpr)));
        float zg = 1.f / (1.f + __expf(-(xz + hpz)));
        float ng = tanhf(xn + rg * hpn);
        float hold = h32_p[(size_t)b * Hdim + i];
        float hnew = (1.f - zg) * ng + zg * hold;
        h32_n[(size_t)b * Hdim + i] = hnew;
        hbf_n[(size_t)b * Hdim + i] = (bf16)hnew;
        y[m * Hdim + i] = (bf16)hnew;
        if (t == Tdim - 1) finals[(size_t)b * Hdim + i] = hnew;
      }
    }
    __threadfence();
    grid.sync();
  }
}

// ---------------- in-place log_softmax over V per row (f32x4) ----------------
__global__ __launch_bounds__(256) void logsoftmax(float* __restrict__ out) {
  __shared__ float sm[256], ss[256];
  int row = blockIdx.x;
  f32x4* x = (f32x4*)(out + (size_t)row * Vdim);   // 8000 vec4
  float m = -1e30f, s = 0.f;
  for (int j = threadIdx.x; j < Vdim / 4; j += 256) {
    f32x4 v = x[j];
#pragma unroll
    for (int e = 0; e < 4; e++) {
      float nm = fmaxf(m, v[e]);
      s = s * __expf(m - nm) + __expf(v[e] - nm);
      m = nm;
    }
  }
  sm[threadIdx.x] = m; ss[threadIdx.x] = s;
  __syncthreads();
  for (int off = 128; off; off >>= 1) {
    if (threadIdx.x < off) {
      float m1 = sm[threadIdx.x], s1 = ss[threadIdx.x];
      float m2 = sm[threadIdx.x + off], s2 = ss[threadIdx.x + off];
      float mm = fmaxf(m1, m2);
      sm[threadIdx.x] = mm;
      ss[threadIdx.x] = s1 * __expf(m1 - mm) + s2 * __expf(m2 - mm);
    }
    __syncthreads();
  }
  float lse = sm[0] + logf(ss[0]);
  for (int j = threadIdx.x; j < Vdim / 4; j += 256) {
    f32x4 v = x[j];
    v[0] -= lse; v[1] -= lse; v[2] -= lse; v[3] -= lse;
    x[j] = v;
  }
}

extern "C" void kernel_launch(void* const* d_in, const int* in_sizes, int n_in,
                              void* d_out, int out_size, void* d_ws, size_t ws_size,
                              hipStream_t stream) {
  const float* enc_hidden = (const float*)d_in[1];
  const int*   target     = (const int*)d_in[2];
  const float* emb        = (const float*)d_in[3];
  const float* W_ih       = (const float*)d_in[4];
  const float* W_hh       = (const float*)d_in[5];
  const float* b_ih       = (const float*)d_in[6];
  const float* b_hh       = (const float*)d_in[7];
  const float* W_out      = (const float*)d_in[8];
  const float* b_out      = (const float*)d_in[9];

  float* out = (float*)d_out;                       // [BT, V]
  float* finals = out + (size_t)BT * Vdim;          // [L, B, H]

  uint8_t* wsp = (uint8_t*)d_ws;
  auto alloc = [&](size_t bytes) {
    uint8_t* p = wsp;
    wsp += (bytes + 255) & ~(size_t)255;
    return p;
  };
  bf16* wih_bf  = (bf16*)alloc((size_t)LAYERS * G3H * Hdim * 2);
  bf16* wout_bf = (bf16*)alloc((size_t)Vdim * Hdim * 2);
  bf16* xA      = (bf16*)alloc((size_t)BT * Hdim * 2);
  bf16* xB      = (bf16*)alloc((size_t)BT * Hdim * 2);
  float* xp     = (float*)alloc((size_t)BT * G3H * 4);
  float* h32a   = (float*)alloc((size_t)Bdim * Hdim * 4);
  float* h32b   = (float*)alloc((size_t)Bdim * Hdim * 4);
  bf16* hbfa    = (bf16*)alloc((size_t)Bdim * Hdim * 2);
  bf16* hbfb    = (bf16*)alloc((size_t)Bdim * Hdim * 2);

  {
    int n4 = LAYERS * G3H * Hdim / 4;
    cvt_f32_bf16<<<(n4 + 255) / 256, 256, 0, stream>>>(W_ih, wih_bf, n4);
    int m4 = Vdim * Hdim / 4;
    cvt_f32_bf16<<<(m4 + 255) / 256, 256, 0, stream>>>(W_out, wout_bf, m4);
  }

  embed_relu<<<BT, 256, 0, stream>>>(target, emb, xA);

  bf16* xin = xA;
  bf16* xout_ = xB;
  for (int l = 0; l < LAYERS; l++) {
    // xp = x @ W_ih[l]^T + b_ih[l] : M=2048, N=3072, K=1024
    gemm_lds<<<dim3(G3H / 128, BT / 128), 256, 0, stream>>>(
        xin, wih_bf + (size_t)l * G3H * Hdim, b_ih + (size_t)l * G3H, xp, BT, G3H, Hdim);
    // persistent GRU layer (cooperative: grid-wide sync between timesteps)
    const float* eh_l  = enc_hidden + (size_t)l * Bdim * Hdim;
    const float* whh_l = W_hh + (size_t)l * G3H * Hdim;
    const float* bhh_l = b_hh + (size_t)l * G3H;
    const float* xp_l  = xp;
    bf16* y_l = xout_;
    float* fin_l = finals + (size_t)l * Bdim * Hdim;
    void* kargs[] = {(void*)&eh_l, (void*)&whh_l, (void*)&bhh_l, (void*)&xp_l,
                     (void*)&h32a, (void*)&h32b, (void*)&hbfa, (void*)&hbfb,
                     (void*)&y_l, (void*)&fin_l};
    hipLaunchCooperativeKernel((void*)gru_layer, dim3(256), dim3(256), kargs, 0, stream);
    bf16* tmp = xin; xin = xout_; xout_ = tmp;
  }

  // logits = x @ W_out^T + b_out : M=2048, N=32000, K=1024
  gemm_lds<<<dim3(Vdim / 128, BT / 128), 256, 0, stream>>>(
      xin, wout_bf, b_out, out, BT, Vdim, Hdim);

  logsoftmax<<<BT, 256, 0, stream>>>(out);
}